// Round 3
// baseline (451.796 us; speedup 1.0000x reference)
//
#include <hip/hip_runtime.h>

#define G_GROUPS 512
#define CNT      8192
#define S_PAIRS  8192
#define BLOCK    256
#define WAVES    (BLOCK / 64)        // 4
#define PPT      16                  // pairs per thread
#define PAIRS_PER_BLOCK (BLOCK * PPT)            // 4096
#define NWG      ((G_GROUPS * S_PAIRS) / PAIRS_PER_BLOCK)   // 1024 blocks
#define NXCD     8

__global__ __launch_bounds__(BLOCK) void rgn_loss_kernel(
    const float* __restrict__ inputs,
    const float* __restrict__ target,
    const int*   __restrict__ left,
    const int*   __restrict__ right,
    float*       __restrict__ out)
{
    __shared__ float red[WAVES];

    const int tid  = threadIdx.x;
    const int lane = tid & 63;
    const int wid  = tid >> 6;

    // XCD-aware swizzle (bijective: NWG % 8 == 0): physical slot p -> XCD p%8;
    // choose logical block = (p%8)*(NWG/8) + p/8 so consecutive logical blocks
    // (same group: 2 blocks/group) land on the same XCD -> slab reuse in L2.
    const int p   = blockIdx.x;
    const int b   = (p % NXCD) * (NWG / NXCD) + p / NXCD;

    // Block b handles pairs [b*4096, (b+1)*4096) — entirely inside group b/2.
    const size_t pbase = (size_t)b * PAIRS_PER_BLOCK;

    // ---- Pair indices: coalesced burst (global indices; no rebasing needed) ----
    int li[PPT], ri[PPT];
    #pragma unroll
    for (int i = 0; i < PPT; ++i) {
        li[i] = left [pbase + tid + i * BLOCK];
        ri[i] = right[pbase + tid + i * BLOCK];
    }

    // ---- Direct gather from global (L2/L3-resident slab), 2-pair pipeline.
    //      Outer loop NOT unrolled: caps in-flight data at 2 pairs x 4 x 16B
    //      = 32 VGPRs, so nothing spills; TLP (24-32 waves/CU) hides latency.
    float acc = 0.0f;
    #pragma unroll 1
    for (int c = 0; c < PPT / 2; ++c) {
        float4 aL0, aR0, bL0, bR0, aL1, aR1, bL1, bR1;
        {
            const int l0 = li[2 * c], r0 = ri[2 * c];
            const int l1 = li[2 * c + 1], r1 = ri[2 * c + 1];
            __builtin_memcpy(&aL0, inputs + (size_t)l0 * 9 + 3, 16);
            __builtin_memcpy(&aR0, inputs + (size_t)r0 * 9 + 3, 16);
            __builtin_memcpy(&bL0, target + (size_t)l0 * 9 + 3, 16);
            __builtin_memcpy(&bR0, target + (size_t)r0 * 9 + 3, 16);
            __builtin_memcpy(&aL1, inputs + (size_t)l1 * 9 + 3, 16);
            __builtin_memcpy(&aR1, inputs + (size_t)r1 * 9 + 3, 16);
            __builtin_memcpy(&bL1, target + (size_t)l1 * 9 + 3, 16);
            __builtin_memcpy(&bR1, target + (size_t)r1 * 9 + 3, 16);
        }
        {
            const float dx = aL0.x - aR0.x, dy = aL0.y - aR0.y, dz = aL0.z - aR0.z;
            const float ex = bL0.x - bR0.x, ey = bL0.y - bR0.y, ez = bL0.z - bR0.z;
            const float d = sqrtf(dx * dx + dy * dy + dz * dz)
                          - sqrtf(ex * ex + ey * ey + ez * ez);
            acc += d * d;
        }
        {
            const float dx = aL1.x - aR1.x, dy = aL1.y - aR1.y, dz = aL1.z - aR1.z;
            const float ex = bL1.x - bR1.x, ey = bL1.y - bR1.y, ez = bL1.z - bR1.z;
            const float d = sqrtf(dx * dx + dy * dy + dz * dz)
                          - sqrtf(ex * ex + ey * ey + ez * ez);
            acc += d * d;
        }
    }

    // ---- Block reduction -> one atomic (1024 atomics total, spread in time) ----
    #pragma unroll
    for (int off = 32; off > 0; off >>= 1)
        acc += __shfl_down(acc, off);
    if (lane == 0) red[wid] = acc;
    __syncthreads();
    if (wid == 0 && lane == 0) {
        float v = red[0] + red[1] + red[2] + red[3];
        atomicAdd(out, v * (1.0f / ((float)G_GROUPS * (float)S_PAIRS)));
    }
}

extern "C" void kernel_launch(void* const* d_in, const int* in_sizes, int n_in,
                              void* d_out, int out_size, void* d_ws, size_t ws_size,
                              hipStream_t stream) {
    const float* inputs = (const float*)d_in[0];
    const float* target = (const float*)d_in[1];
    const int*   left   = (const int*)d_in[2];
    const int*   right  = (const int*)d_in[3];
    float*       out    = (float*)d_out;

    hipMemsetAsync(out, 0, sizeof(float), stream);   // graph-capture safe
    rgn_loss_kernel<<<NWG, BLOCK, 0, stream>>>(inputs, target, left, right, out);
}

// Round 4
// 329.691 us; speedup vs baseline: 1.3704x; 1.3704x over previous
//
#include <hip/hip_runtime.h>

#define G_GROUPS 512
#define CNT      8192
#define S_PAIRS  8192
#define BLOCK    1024
#define WAVES    (BLOCK / 64)        // 16
#define PPT      (S_PAIRS / BLOCK)   // 8 pairs per thread
#define RPT      (CNT / BLOCK)       // 8 records per thread per tensor

// Load one CA row (16 B at record byte offset 36r+12; 4B-aligned) into a float4.
#define LOADCA(dst, src, rec)                                         \
    __builtin_memcpy(&(dst), (src) + (size_t)(rec) * 9 + 3, 16)

__global__ __launch_bounds__(BLOCK, 4) void rgn_loss_kernel(
    const float* __restrict__ inputs,
    const float* __restrict__ target,
    const int*   __restrict__ left,
    const int*   __restrict__ right,
    float*       __restrict__ out)
{
    // CA-row table, one tensor at a time: 8192 x float4 = 128 KiB.
    __shared__ float4 tab4[CNT];
    __shared__ float  red[WAVES];

    const int tid   = threadIdx.x;
    const int lane  = tid & 63;
    const int wid   = tid >> 6;
    const int g     = blockIdx.x;
    const int gbase = g * CNT;

    // ---- Pair indices: 16 coalesced dword loads (fly with the input stage) ----
    const size_t pbase = (size_t)g * S_PAIRS;
    int li[PPT], ri[PPT];
    #pragma unroll
    for (int i = 0; i < PPT; ++i) {
        li[i] = left [pbase + tid + i * BLOCK] - gbase;   // group-local by construction
        ri[i] = right[pbase + tid + i * BLOCK] - gbase;
    }

    // ---- Stage inputs: reg-staged VMEM (NOT global_load_lds — that path
    //      services ~1 instr/CU at full latency, capping staging at 1.3 TB/s).
    //      8 independent dwordx4 per thread -> 128 KiB in flight per CU.
    //      Named scalars: no array, no scratch risk (round-2 post-mortem).
    float4 iv0, iv1, iv2, iv3, iv4, iv5, iv6, iv7;
    LOADCA(iv0, inputs, gbase + tid + 0 * BLOCK);
    LOADCA(iv1, inputs, gbase + tid + 1 * BLOCK);
    LOADCA(iv2, inputs, gbase + tid + 2 * BLOCK);
    LOADCA(iv3, inputs, gbase + tid + 3 * BLOCK);
    LOADCA(iv4, inputs, gbase + tid + 4 * BLOCK);
    LOADCA(iv5, inputs, gbase + tid + 5 * BLOCK);
    LOADCA(iv6, inputs, gbase + tid + 6 * BLOCK);
    LOADCA(iv7, inputs, gbase + tid + 7 * BLOCK);
    tab4[tid + 0 * BLOCK] = iv0;
    tab4[tid + 1 * BLOCK] = iv1;
    tab4[tid + 2 * BLOCK] = iv2;
    tab4[tid + 3 * BLOCK] = iv3;
    tab4[tid + 4 * BLOCK] = iv4;
    tab4[tid + 5 * BLOCK] = iv5;
    tab4[tid + 6 * BLOCK] = iv6;
    tab4[tid + 7 * BLOCK] = iv7;
    __syncthreads();                       // inputs table published

    // ---- Issue ALL target loads now; they retire under the d_in gather.
    //      32 VGPRs live across the gather — fits the 128-reg budget easily.
    float4 tv0, tv1, tv2, tv3, tv4, tv5, tv6, tv7;
    LOADCA(tv0, target, gbase + tid + 0 * BLOCK);
    LOADCA(tv1, target, gbase + tid + 1 * BLOCK);
    LOADCA(tv2, target, gbase + tid + 2 * BLOCK);
    LOADCA(tv3, target, gbase + tid + 3 * BLOCK);
    LOADCA(tv4, target, gbase + tid + 4 * BLOCK);
    LOADCA(tv5, target, gbase + tid + 5 * BLOCK);
    LOADCA(tv6, target, gbase + tid + 6 * BLOCK);
    LOADCA(tv7, target, gbase + tid + 7 * BLOCK);

    // ---- Gather d_in, park in VGPRs ----
    float din[PPT];
    #pragma unroll
    for (int i = 0; i < PPT; ++i) {
        const float4 L = tab4[li[i]];
        const float4 R = tab4[ri[i]];
        const float dx = L.x - R.x;
        const float dy = L.y - R.y;
        const float dz = L.z - R.z;
        din[i] = sqrtf(dx * dx + dy * dy + dz * dz);
    }
    __syncthreads();                       // all gather reads done before overwrite

    // ---- Publish target table (loads long since landed) ----
    tab4[tid + 0 * BLOCK] = tv0;
    tab4[tid + 1 * BLOCK] = tv1;
    tab4[tid + 2 * BLOCK] = tv2;
    tab4[tid + 3 * BLOCK] = tv3;
    tab4[tid + 4 * BLOCK] = tv4;
    tab4[tid + 5 * BLOCK] = tv5;
    tab4[tid + 6 * BLOCK] = tv6;
    tab4[tid + 7 * BLOCK] = tv7;
    __syncthreads();

    // ---- Gather d_tg, accumulate squared difference ----
    float acc = 0.0f;
    #pragma unroll
    for (int i = 0; i < PPT; ++i) {
        const float4 L = tab4[li[i]];
        const float4 R = tab4[ri[i]];
        const float dx = L.x - R.x;
        const float dy = L.y - R.y;
        const float dz = L.z - R.z;
        const float d  = din[i] - sqrtf(dx * dx + dy * dy + dz * dz);
        acc += d * d;
    }

    // ---- Block reduction -> one atomic ----
    #pragma unroll
    for (int off = 32; off > 0; off >>= 1)
        acc += __shfl_down(acc, off);
    if (lane == 0) red[wid] = acc;
    __syncthreads();
    if (wid == 0) {
        float v = (lane < WAVES) ? red[lane] : 0.0f;
        #pragma unroll
        for (int off = 8; off > 0; off >>= 1)
            v += __shfl_down(v, off);
        if (lane == 0)
            atomicAdd(out, v * (1.0f / ((float)G_GROUPS * (float)S_PAIRS)));
    }
}

extern "C" void kernel_launch(void* const* d_in, const int* in_sizes, int n_in,
                              void* d_out, int out_size, void* d_ws, size_t ws_size,
                              hipStream_t stream) {
    const float* inputs = (const float*)d_in[0];
    const float* target = (const float*)d_in[1];
    const int*   left   = (const int*)d_in[2];
    const int*   right  = (const int*)d_in[3];
    float*       out    = (float*)d_out;

    hipMemsetAsync(out, 0, sizeof(float), stream);   // graph-capture safe
    rgn_loss_kernel<<<G_GROUPS, BLOCK, 0, stream>>>(inputs, target, left, right, out);
}